// Round 9
// baseline (219.074 us; speedup 1.0000x reference)
//
#include <hip/hip_runtime.h>

// SelfAttention block:
//   gram_v5 : Graw slabs = x @ x^T per (b,K-slice,col-quarter). 4-wave blocks,
//             acc 64 regs -> 3-4 blocks/CU TLP; same-XCD quarters share x via L2.
//   prep2   : group stats -> sc/sh, rall(q,k), u/v correction vectors
//   gsum2   : Graw[b] = sum of 8 slabs -> f16 h|l planes
//   wvt2    : Wv^T -> f16 (tiled transpose)
//   logits2 : T1=(Wq*sc)@Graw, L=T1@(Wk*sc)^T + rank-2 corr, softmax, A^T, cv
//   fused_s : T2=Pw@A, S'=(T2@Wv)*sc -> f16, const2
//   final_v4: out = x(f16 LDS) + S'@x + const2; swizzled b128 reads

#define B_ 32
#define C_ 256
#define N_ 4096
#define GSIZE (32 * N_)
#define EPSV 1e-5f
#define SCALE 0.0625f

// workspace layout (float units)
#define OFF_SC    0
#define OFF_SH    8192
#define OFF_RS    16384
#define OFF_RSP   24576                 // [b*8+ks][256]
#define OFF_SQP   90112                 // [b*8+ks][256]
#define OFF_RALL  155648                // [b][768] (q,k used)
#define OFF_UV    180224                // [b][4][256] = uq,vq,uk,vk
#define OFF_CV    212992
#define OFF_CONST 221184
#define OFF_WVT   229376                // f16 [256][256]
#define OFF_GH    262144                // f16 [b][256][256] high
#define OFF_GL    1310720               // f16 [b][256][256] low
#define OFF_AT    2359296               // fp32 [b][j][r]
#define OFF_S16   4456448               // f16 [b][o][c]  (S' = S*sc)
#define OFF_GP    5505024               // f16 slabs [b*8+ks][65536]

typedef _Float16 half_t;
typedef half_t f16x8 __attribute__((ext_vector_type(8)));
typedef float f32x16 __attribute__((ext_vector_type(16)));

// ---------------- Gram v5: 4-wave blocks, col-quarter split -----------------
// grid 1024: slice = bid&255 (b = slice>>3, ks = slice&7, K=512), q = bid>>8.
// Block output: rows 0..255 x cols q*64..+64. Chunk = 32 k, dbuf 2x16KB LDS.
// Pipeline per chunk: issue load(c+1) -> MFMA(c) -> write(c+1) -> sync.
// Stalls covered by 3-4 blocks/CU (TLP). Quarter 0 also emits rs/rq partials.
__global__ __launch_bounds__(256) void gram_v5_k(const float* __restrict__ x,
                                                 float* __restrict__ ws) {
  __shared__ __align__(16) char hb[2][16384];  // [buf][256 rows][64B]
  int bid = blockIdx.x;
  int slice = bid & 255, q = bid >> 8;
  int b = slice >> 3, ks = slice & 7;
  int t = threadIdx.x;
  const float* xb = x + (size_t)b * (C_ * (size_t)N_) + ks * 512;
  int lane = t & 63, w = t >> 6;
  int r31 = lane & 31, hi = lane >> 5;
  int lrow = t >> 3, lc4 = t & 7;  // thread stages rows lrow+32p, float4 col lc4
  const float* lbase = xb + (size_t)lrow * N_ + lc4 * 4;
  f32x16 acc[2][2] = {};
  float4 stg[8];
  float rs[8] = {0.f, 0.f, 0.f, 0.f, 0.f, 0.f, 0.f, 0.f};
  float rq[8] = {0.f, 0.f, 0.f, 0.f, 0.f, 0.f, 0.f, 0.f};

#define G5_LOAD(c)                                                        \
  _Pragma("unroll") for (int p = 0; p < 8; ++p)                           \
      stg[p] = *(const float4*)(lbase + (size_t)p * 32 * N_ + (c) * 32);

#define G5_WRITE(buf)                                                     \
  {                                                                       \
    char* bp = hb[buf];                                                   \
    _Pragma("unroll") for (int p = 0; p < 8; ++p) {                       \
      float4 v = stg[p];                                                  \
      rs[p] += v.x + v.y + v.z + v.w;                                     \
      rq[p] += v.x * v.x + v.y * v.y + v.z * v.z + v.w * v.w;             \
      union { half_t h[4]; uint2 u; } H;                                  \
      H.h[0] = (half_t)v.x; H.h[1] = (half_t)v.y;                         \
      H.h[2] = (half_t)v.z; H.h[3] = (half_t)v.w;                         \
      int row = lrow + p * 32;                                            \
      int g = (lc4 >> 1) ^ (row & 3);                                     \
      *(uint2*)(bp + row * 64 + g * 16 + (lc4 & 1) * 8) = H.u;            \
    }                                                                     \
  }

  G5_LOAD(0);
  G5_WRITE(0);
  __syncthreads();
  for (int c = 0; c < 16; ++c) {
    if (c < 15) G5_LOAD(c + 1);
    const char* bp = hb[c & 1];
#pragma unroll
    for (int kk = 0; kk < 2; ++kk) {
      int g4 = kk * 2 + hi;  // granule index 0..3
      f16x8 Af[2], Bf[2];
#pragma unroll
      for (int m = 0; m < 2; ++m) {
        int row = w * 64 + m * 32 + r31;
        Af[m] = *(const f16x8*)(bp + row * 64 + ((g4 ^ (row & 3)) * 16));
      }
#pragma unroll
      for (int n = 0; n < 2; ++n) {
        int row = q * 64 + n * 32 + r31;
        Bf[n] = *(const f16x8*)(bp + row * 64 + ((g4 ^ (row & 3)) * 16));
      }
#pragma unroll
      for (int m = 0; m < 2; ++m)
#pragma unroll
        for (int n = 0; n < 2; ++n)
          acc[m][n] = __builtin_amdgcn_mfma_f32_32x32x16_f16(Af[m], Bf[n], acc[m][n], 0, 0, 0);
    }
    if (c < 15) G5_WRITE((c + 1) & 1);
    __syncthreads();
  }
  // per-channel sum/sumsq partials (quarter 0 only; all quarters identical)
  if (q == 0) {
#pragma unroll
    for (int p = 0; p < 8; ++p) {
      float s = rs[p], qq = rq[p];
      s += __shfl_xor(s, 1); s += __shfl_xor(s, 2); s += __shfl_xor(s, 4);
      qq += __shfl_xor(qq, 1); qq += __shfl_xor(qq, 2); qq += __shfl_xor(qq, 4);
      if ((t & 7) == 0) {
        int row = lrow + p * 32;
        ws[OFF_RSP + (size_t)slice * 256 + row] = s;
        ws[OFF_SQP + (size_t)slice * 256 + row] = qq;
      }
    }
  }
  // partial G -> f16 slab (disjoint column range per quarter, no atomics)
  half_t* Gp = (half_t*)(ws + OFF_GP) + (size_t)slice * 65536;
#pragma unroll
  for (int m = 0; m < 2; ++m)
#pragma unroll
    for (int n = 0; n < 2; ++n)
#pragma unroll
      for (int r = 0; r < 16; ++r) {
        int gr = w * 64 + m * 32 + (r & 3) + 8 * (r >> 2) + 4 * hi;
        int gc = q * 64 + n * 32 + r31;
        Gp[gr * 256 + gc] = (half_t)acc[m][n][r];
      }
#undef G5_LOAD
#undef G5_WRITE
}

// ---------------- gsum2: Graw = sum of slabs -> f16 h|l planes --------------
__global__ __launch_bounds__(256) void gsum2_k(float* __restrict__ ws) {
  int bx = blockIdx.x;  // 2048 = 32 b x 64 seg
  int b = bx >> 6, seg = bx & 63;
  int e0 = seg * 1024 + threadIdx.x * 4;
  const half_t* Gp = (const half_t*)(ws + OFF_GP) + (size_t)b * 8 * 65536 + e0;
  float s[4] = {0.f, 0.f, 0.f, 0.f};
#pragma unroll
  for (int ks = 0; ks < 8; ++ks) {
    union { uint2 u; half_t h[4]; } P;
    P.u = *(const uint2*)(Gp + (size_t)ks * 65536);
#pragma unroll
    for (int i = 0; i < 4; ++i) s[i] += (float)P.h[i];
  }
  union { half_t h[4]; uint2 u; } H, L;
#pragma unroll
  for (int i = 0; i < 4; ++i) {
    H.h[i] = (half_t)s[i];
    L.h[i] = (half_t)(s[i] - (float)H.h[i]);
  }
  *(uint2*)((half_t*)(ws + OFF_GH) + (size_t)b * 65536 + e0) = H.u;
  *(uint2*)((half_t*)(ws + OFF_GL) + (size_t)b * 65536 + e0) = L.u;
}

// ---------------- prep2: stats, sc/sh, rall(q,k), u/v vectors ---------------
__global__ __launch_bounds__(256) void prep2_k(const float* __restrict__ gw,
                                               const float* __restrict__ gb,
                                               const float* __restrict__ qkvw,
                                               float* __restrict__ ws) {
  int b = blockIdx.x, t = threadIdx.x;
  __shared__ float sL[256], qL[256], svecs[256], scrs[256], shsm[256];
  __shared__ float gmean[8], grstd[8];
  float s = 0.f, q = 0.f;
#pragma unroll
  for (int ks = 0; ks < 8; ++ks) {
    s += ws[OFF_RSP + (b * 8 + ks) * 256 + t];
    q += ws[OFF_SQP + (b * 8 + ks) * 256 + t];
  }
  ws[OFF_RS + b * 256 + t] = s;
  sL[t] = s; qL[t] = q;
  __syncthreads();
  if (t < 8) {
    float gs = 0.f, gq = 0.f;
    for (int i = 0; i < 32; ++i) { gs += sL[t * 32 + i]; gq += qL[t * 32 + i]; }
    float mean = gs * (1.f / GSIZE);
    float var = gq * (1.f / GSIZE) - mean * mean;
    gmean[t] = mean;
    grstd[t] = rsqrtf(var + EPSV);
  }
  __syncthreads();
  int g = t >> 5;
  float sc = grstd[g] * gw[t];
  float sh = gb[t] - gmean[g] * sc;
  ws[OFF_SC + b * 256 + t] = sc;
  ws[OFF_SH + b * 256 + t] = sh;
  svecs[t] = s * sc + 4096.f * sh;
  scrs[t] = s * sc;   // sc .* rs
  shsm[t] = sh;
  __syncthreads();
  {
    const float* r1 = qkvw + (size_t)t * 256;
    float rq = 0.f, uq = 0.f, vq = 0.f;
#pragma unroll 4
    for (int c = 0; c < 256; ++c) {
      float wv = r1[c];
      rq += wv * svecs[c]; uq += wv * scrs[c]; vq += wv * shsm[c];
    }
    ws[OFF_RALL + b * 768 + t] = rq;
    ws[OFF_UV + b * 1024 + t] = uq;
    ws[OFF_UV + b * 1024 + 256 + t] = vq;
  }
  {
    const float* r2 = qkvw + (size_t)(256 + t) * 256;
    float rk = 0.f, uk = 0.f, vk = 0.f;
#pragma unroll 4
    for (int c = 0; c < 256; ++c) {
      float wv = r2[c];
      rk += wv * svecs[c]; uk += wv * scrs[c]; vk += wv * shsm[c];
    }
    ws[OFF_RALL + b * 768 + 256 + t] = rk;
    ws[OFF_UV + b * 1024 + 512 + t] = uk;
    ws[OFF_UV + b * 1024 + 768 + t] = vk;
  }
}

// ---------------- wvt2: tiled transpose Wv -> f16 WVT[e][d] -----------------
__global__ __launch_bounds__(256) void wvt2_k(const float* __restrict__ qkvw,
                                              float* __restrict__ ws) {
  __shared__ float sm[64][68];
  int be = blockIdx.x * 64, bd = blockIdx.y * 64;
  int t = threadIdx.x;
#pragma unroll
  for (int i = 0; i < 4; ++i) {
    int f = t + i * 256;
    int row = f >> 4, c4 = f & 15;  // row = d-local
    float4 v = *(const float4*)(qkvw + (size_t)(512 + bd + row) * 256 + be + c4 * 4);
    sm[row][c4 * 4 + 0] = v.x; sm[row][c4 * 4 + 1] = v.y;
    sm[row][c4 * 4 + 2] = v.z; sm[row][c4 * 4 + 3] = v.w;
  }
  __syncthreads();
  half_t* WVT = (half_t*)(ws + OFF_WVT);
#pragma unroll
  for (int i = 0; i < 4; ++i) {
    int f = t + i * 256;
    int el = f >> 4, d4 = (f & 15) * 4;
    union { half_t h[4]; uint2 u; } P;
#pragma unroll
    for (int k = 0; k < 4; ++k) P.h[k] = (half_t)sm[d4 + k][el];
    *(uint2*)(WVT + (size_t)(be + el) * 256 + bd + d4) = P.u;
  }
}

// ---------------- logits2: T1=(Wq sc)@Graw, L=T1@(Wk sc)^T, softmax ---------
__global__ __launch_bounds__(256) void logits2_k(
    const float* __restrict__ qkvw, const float* __restrict__ qkvb,
    float* __restrict__ ws) {
  int b = blockIdx.y, r0 = blockIdx.x * 32;
  int t = threadIdx.x, lane = t & 63, w = t >> 6, r31 = lane & 31, hi = lane >> 5;
  __shared__ __align__(16) char GHL[32768];  // [256][128B]
  __shared__ __align__(16) char AHL[8192];
  __shared__ float T1s[32][257];
  __shared__ float scs[256];
  __shared__ float bk_s[256], rk_s[256], uk_s[256], vk_s[256];
  __shared__ float bq_s[32], rq_s[32], uq_s[32], vq_s[32];
  scs[t] = ws[OFF_SC + b * 256 + t];
  bk_s[t] = qkvb[256 + t];
  rk_s[t] = ws[OFF_RALL + b * 768 + 256 + t];
  uk_s[t] = ws[OFF_UV + b * 1024 + 512 + t];
  vk_s[t] = ws[OFF_UV + b * 1024 + 768 + t];
  if (t < 32) {
    bq_s[t] = qkvb[r0 + t];
    rq_s[t] = ws[OFF_RALL + b * 768 + r0 + t];
    uq_s[t] = ws[OFF_UV + b * 1024 + r0 + t];
    vq_s[t] = ws[OFF_UV + b * 1024 + 256 + r0 + t];
  }
  __syncthreads();
  const half_t* Gh = (const half_t*)(ws + OFF_GH) + (size_t)b * 65536;
  const half_t* Gl = (const half_t*)(ws + OFF_GL) + (size_t)b * 65536;
  f32x16 acc[2] = {};
  // ---- step A: T1 = (Wq*sc) @ Graw, K=256, 32-k chunks ----
  for (int k0 = 0; k0 < 256; k0 += 32) {
    {  // A: Wq rows r0..+31, column-scaled, h-only
      int row = t >> 3, c4 = t & 7;
      float4 v = *(const float4*)(qkvw + (size_t)(r0 + row) * 256 + k0 + c4 * 4);
      union { half_t h[4]; uint2 u; } H;
      H.h[0] = (half_t)(v.x * scs[k0 + c4 * 4 + 0]);
      H.h[1] = (half_t)(v.y * scs[k0 + c4 * 4 + 1]);
      H.h[2] = (half_t)(v.z * scs[k0 + c4 * 4 + 2]);
      H.h[3] = (half_t)(v.w * scs[k0 + c4 * 4 + 3]);
      int s8 = row & 7;
      *(uint2*)(AHL + row * 128 + (((c4 >> 1) ^ s8) * 16) + (c4 & 1) * 8) = H.u;
    }
    {  // B: Graw rows (symmetric) from h|l planes — straight copy
#pragma unroll
      for (int p = 0; p < 8; ++p) {
        int f = t + p * 256;
        int row = f >> 3, ko = f & 7;
        const half_t* src = (ko < 4) ? Gh : Gl;
        uint4 v = *(const uint4*)(src + (size_t)row * 256 + k0 + (ko & 3) * 8);
        *(uint4*)(GHL + row * 128 + ((ko ^ (row & 7)) * 16)) = v;
      }
    }
    __syncthreads();
#pragma unroll
    for (int kk = 0; kk < 2; ++kk) {
      int kb = kk * 32 + hi * 16;
      int arow = r31;
      f16x8 Aq = *(const f16x8*)(AHL + arow * 128 + (((kb >> 4) ^ (arow & 7)) * 16));
#pragma unroll
      for (int n = 0; n < 2; ++n) {
        int row = w * 64 + n * 32 + r31;
        int s8 = row & 7;
        f16x8 Bh = *(const f16x8*)(GHL + row * 128 + (((kb >> 4) ^ s8) * 16));
        f16x8 Bl = *(const f16x8*)(GHL + row * 128 + ((((kb >> 4) + 4) ^ s8) * 16));
        acc[n] = __builtin_amdgcn_mfma_f32_32x32x16_f16(Aq, Bh, acc[n], 0, 0, 0);
        acc[n] = __builtin_amdgcn_mfma_f32_32x32x16_f16(Aq, Bl, acc[n], 0, 0, 0);
      }
    }
    __syncthreads();
  }
#pragma unroll
  for (int n = 0; n < 2; ++n)
#pragma unroll
    for (int r = 0; r < 16; ++r)
      T1s[(r & 3) + 8 * (r >> 2) + 4 * hi][w * 64 + n * 32 + r31] = acc[n][r];
  __syncthreads();
  // ---- step B: L = T1 @ (Wk*sc)^T, K=256, 64-k chunks ----
  f32x16 acc2[2] = {};
  for (int k0 = 0; k0 < 256; k0 += 64) {
    {  // T1 rows 0..31 h|l, 16-slot swizzle
      int row = t >> 3;
#pragma unroll
      for (int u = 0; u < 2; ++u) {
        int c4 = (t & 7) + u * 8;
        float vv[4];
#pragma unroll
        for (int j = 0; j < 4; ++j) vv[j] = T1s[row][k0 + c4 * 4 + j];
        union { half_t h[4]; uint2 u2; } H, L;
#pragma unroll
        for (int j = 0; j < 4; ++j) {
          half_t h = (half_t)vv[j];
          H.h[j] = h; L.h[j] = (half_t)(vv[j] - (float)h);
        }
        int s16 = row & 15;
        *(uint2*)(AHL + row * 256 + (((c4 >> 1) ^ s16) * 16) + (c4 & 1) * 8) = H.u2;
        *(uint2*)(AHL + row * 256 + ((((c4 >> 1) + 8) ^ s16) * 16) + (c4 & 1) * 8) = L.u2;
      }
    }
    {  // Wk rows, column-scaled, h-only
#pragma unroll
      for (int p = 0; p < 16; ++p) {
        int f = t + p * 256;
        int row = f >> 4, c4 = f & 15;
        float4 v = *(const float4*)(qkvw + (size_t)(256 + row) * 256 + k0 + c4 * 4);
        union { half_t h[4]; uint2 u; } H;
        H.h[0] = (half_t)(v.x * scs[k0 + c4 * 4 + 0]);
        H.h[1] = (half_t)(v.y * scs[k0 + c4 * 4 + 1]);
        H.h[2] = (half_t)(v.z * scs[k0 + c4 * 4 + 2]);
        H.h[3] = (half_t)(v.w * scs[k0 + c4 * 4 + 3]);
        int slot = (c4 >> 1) ^ (row & 7);
        *(uint2*)(GHL + row * 128 + slot * 16 + (c4 & 1) * 8) = H.u;
      }
    }
    __syncthreads();
#pragma unroll
    for (int kk = 0; kk < 4; ++kk) {
      int kb = kk * 32 + hi * 16;
      int arow = r31;
      int s16 = arow & 15;
      f16x8 Ah = *(const f16x8*)(AHL + arow * 256 + (((kb >> 4) ^ s16) * 16));
      f16x8 Al = *(const f16x8*)(AHL + arow * 256 + ((((kb >> 4) + 8) ^ s16) * 16));
#pragma unroll
      for (int n = 0; n < 2; ++n) {
        int row = w * 64 + n * 32 + r31;
        f16x8 Bf = *(const f16x8*)(GHL + row * 128 + (((kb >> 4) ^ (row & 7)) * 16));
        acc2[n] = __builtin_amdgcn_mfma_f32_32x32x16_f16(Ah, Bf, acc2[n], 0, 0, 0);
        acc2[n] = __builtin_amdgcn_mfma_f32_32x32x16_f16(Al, Bf, acc2[n], 0, 0, 0);
      }
    }
    __syncthreads();
  }
  // rank-2 + bias corrections, store logits
#pragma unroll
  for (int n = 0; n < 2; ++n)
#pragma unroll
    for (int r = 0; r < 16; ++r) {
      int rr = (r & 3) + 8 * (r >> 2) + 4 * hi;
      int cc = w * 64 + n * 32 + r31;
      float v = acc2[n][r];
      float ukv = uk_s[cc] + 4096.f * vk_s[cc];
      v = (v + uq_s[rr] * vk_s[cc] + vq_s[rr] * ukv + bq_s[rr] * rk_s[cc] +
           bk_s[cc] * (rq_s[rr] + 4096.f * bq_s[rr])) * SCALE;
      T1s[rr][cc] = v;
    }
  __syncthreads();
  bk_s[t] = qkvb[512 + t];
  __syncthreads();
  {  // softmax: 8 threads per row
    int row = t >> 3, ls = t & 7;
    float m = -1e30f;
#pragma unroll
    for (int i = 0; i < 32; ++i) m = fmaxf(m, T1s[row][ls + i * 8]);
    m = fmaxf(m, __shfl_xor(m, 1));
    m = fmaxf(m, __shfl_xor(m, 2));
    m = fmaxf(m, __shfl_xor(m, 4));
    float s = 0.f, cvp = 0.f;
#pragma unroll
    for (int i = 0; i < 32; ++i) {
      int col = ls + i * 8;
      float e = __expf(T1s[row][col] - m);
      T1s[row][col] = e;
      s += e;
      cvp += e * bk_s[col];
    }
    s += __shfl_xor(s, 1); s += __shfl_xor(s, 2); s += __shfl_xor(s, 4);
    cvp += __shfl_xor(cvp, 1); cvp += __shfl_xor(cvp, 2); cvp += __shfl_xor(cvp, 4);
    float inv = 1.f / s;
#pragma unroll
    for (int i = 0; i < 32; ++i) T1s[row][ls + i * 8] *= inv;
    if (ls == 0) ws[OFF_CV + b * 256 + r0 + row] = cvp * inv;
  }
  __syncthreads();
  {  // transposed write: AT[b][j][r0..r0+31]
    float* ATb = ws + OFF_AT + (size_t)b * 65536;
#pragma unroll
    for (int u = 0; u < 8; ++u) {
      float4 v = {T1s[u * 4 + 0][t], T1s[u * 4 + 1][t], T1s[u * 4 + 2][t],
                  T1s[u * 4 + 3][t]};
      *(float4*)(ATb + (size_t)t * 256 + r0 + u * 4) = v;
    }
  }
}

// ---------------- fused S: T2=Pw@A, S'=(T2@Wv)*sc f16, const2 ---------------
__global__ __launch_bounds__(256) void fused_s_k(const float* __restrict__ pw,
                                                 const float* __restrict__ pb,
                                                 float* __restrict__ ws) {
  int b = blockIdx.y, r0 = blockIdx.x * 32;
  int t = threadIdx.x, lane = t & 63, w = t >> 6, r31 = lane & 31, hi = lane >> 5;
  __shared__ __align__(16) char GHL[32768];
  __shared__ __align__(16) char AHL[8192];
  __shared__ float T1s[32][257];
  __shared__ float cvs[256], scv[256], shv[256];
  cvs[t] = ws[OFF_CV + b * 256 + t];
  scv[t] = ws[OFF_SC + b * 256 + t];
  shv[t] = ws[OFF_SH + b * 256 + t];
  __syncthreads();
  const float* ATb = ws + OFF_AT + (size_t)b * 65536;
  f32x16 acc[2] = {};
  for (int k0 = 0; k0 < 256; k0 += 64) {
    {
#pragma unroll
      for (int p = 0; p < 2; ++p) {
        int f = t + p * 256;
        int row = f >> 4, c4 = f & 15;
        float4 v = *(const float4*)(pw + (size_t)(r0 + row) * 256 + k0 + c4 * 4);
        union { half_t h[4]; uint2 u; } H;
        H.h[0] = (half_t)v.x; H.h[1] = (half_t)v.y;
        H.h[2] = (half_t)v.z; H.h[3] = (half_t)v.w;
        int slot = (c4 >> 1) ^ (row & 7);
        *(uint2*)(AHL + row * 128 + slot * 16 + (c4 & 1) * 8) = H.u;
      }
    }
    {
#pragma unroll
      for (int p = 0; p < 16; ++p) {
        int f = t + p * 256;
        int row = f >> 4, c4 = f & 15;
        float4 v = *(const float4*)(ATb + (size_t)row * 256 + k0 + c4 * 4);
        union { half_t h[4]; uint2 u; } H;
        H.h[0] = (half_t)v.x; H.h[1] = (half_t)v.y;
        H.h[2] = (half_t)v.z; H.h[3] = (half_t)v.w;
        int slot = (c4 >> 1) ^ (row & 7);
        *(uint2*)(GHL + row * 128 + slot * 16 + (c4 & 1) * 8) = H.u;
      }
    }
    __syncthreads();
#pragma unroll
    for (int kk = 0; kk < 4; ++kk) {
      int kb = kk * 32 + hi * 16;
      int arow = r31;
      f16x8 Af = *(const f16x8*)(AHL + arow * 128 + (((kb >> 4) ^ (arow & 7)) * 16));
#pragma unroll
      for (int n = 0; n < 2; ++n) {
        int row = w * 64 + n * 32 + r31;
        f16x8 Bf = *(const f16x8*)(GHL + row * 128 + (((kb >> 4) ^ (row & 7)) * 16));
        acc[n] = __builtin_amdgcn_mfma_f32_32x32x16_f16(Af, Bf, acc[n], 0, 0, 0);
      }
    }
    __syncthreads();
  }
#pragma unroll
  for (int n = 0; n < 2; ++n)
#pragma unroll
    for (int r = 0; r < 16; ++r)
      T1s[(r & 3) + 8 * (r >> 2) + 4 * hi][w * 64 + n * 32 + r31] = acc[n][r];
  __syncthreads();
  float cfull = 0.f;
  {
    int row = t >> 3, ls = t & 7;
    float a = 0.f;
#pragma unroll
    for (int i = 0; i < 32; ++i) {
      int c = ls + i * 8;
      a += pw[(size_t)(r0 + row) * 256 + c] * cvs[c];
    }
    a += __shfl_xor(a, 1); a += __shfl_xor(a, 2); a += __shfl_xor(a, 4);
    cfull = a + pb[r0 + row];
  }
  const half_t* WVT = (const half_t*)(ws + OFF_WVT);
  f32x16 acc2[2] = {};
  for (int k0 = 0; k0 < 256; k0 += 64) {
    {
      int row = t >> 3;
#pragma unroll
      for (int u = 0; u < 2; ++u) {
        int c4 = (t & 7) + u * 8;
        float vv[4];
#pragma unroll
        for (int j = 0; j < 4; ++j) vv[j] = T1s[row][k0 + c4 * 4 + j];
        union { half_t h[4]; uint2 u2; } H, L;
#pragma unroll
        for (int j = 0; j < 4; ++j) {
          half_t h = (half_t)vv[j];
          H.h[j] = h; L.h[j] = (half_t)(vv[j] - (float)h);
        }
        int s16 = row & 15;
        *(uint2*)(AHL + row * 256 + (((c4 >> 1) ^ s16) * 16) + (c4 & 1) * 8) = H.u2;
        *(uint2*)(AHL + row * 256 + ((((c4 >> 1) + 8) ^ s16) * 16) + (c4 & 1) * 8) = L.u2;
      }
    }
    {
#pragma unroll
      for (int p = 0; p < 8; ++p) {
        int f = t + p * 256;
        int row = f >> 3, h8 = f & 7;
        uint2 v = *(const uint2*)(WVT + (size_t)row * 256 + k0 + h8 * 8);
        uint2 v2 = *(const uint2*)(WVT + (size_t)row * 256 + k0 + h8 * 8 + 4);
        int slot = h8 ^ (row & 7);
        *(uint2*)(GHL + row * 128 + slot * 16) = v;
        *(uint2*)(GHL + row * 128 + slot * 16 + 8) = v2;
      }
    }
    __syncthreads();
#pragma unroll
    for (int kk = 0; kk < 4; ++kk) {
      int kb = kk * 32 + hi * 16;
      int arow = r31;
      int s16 = arow & 15;
      f16x8 Ah = *(const f16x8*)(AHL + arow * 256 + (((kb >> 4) ^ s16) * 16));
      f16x8 Al = *(const f16x8*)(AHL + arow * 256 + ((((kb >> 4) + 8) ^ s16) * 16));
#pragma unroll
      for (int n = 0; n < 2; ++n) {
        int row = w * 64 + n * 32 + r31;
        f16x8 Bf = *(const f16x8*)(GHL + row * 128 + (((kb >> 4) ^ (row & 7)) * 16));
        acc2[n] = __builtin_amdgcn_mfma_f32_32x32x16_f16(Ah, Bf, acc2[n], 0, 0, 0);
        acc2[n] = __builtin_amdgcn_mfma_f32_32x32x16_f16(Al, Bf, acc2[n], 0, 0, 0);
      }
    }
    __syncthreads();
  }
#pragma unroll
  for (int n = 0; n < 2; ++n)
#pragma unroll
    for (int r = 0; r < 16; ++r)
      T1s[(r & 3) + 8 * (r >> 2) + 4 * hi][w * 64 + n * 32 + r31] = acc2[n][r];
  __syncthreads();
  {
    half_t* Sb = (half_t*)(ws + OFF_S16) + (size_t)b * 65536;
    int row = t >> 3, seg = t & 7;
    float dsh = 0.f;
#pragma unroll
    for (int u = 0; u < 4; ++u) {
      union { half_t h[8]; uint4 v; } P;
#pragma unroll
      for (int j = 0; j < 8; ++j) {
        int col = seg * 32 + u * 8 + j;
        float sv = T1s[row][col];
        dsh += sv * shv[col];
        P.h[j] = (half_t)(sv * scv[col]);
      }
      *(uint4*)(Sb + (size_t)(r0 + row) * 256 + seg * 32 + u * 8) = P.v;
    }
    dsh += __shfl_xor(dsh, 1); dsh += __shfl_xor(dsh, 2); dsh += __shfl_xor(dsh, 4);
    if (seg == 0) ws[OFF_CONST + b * 256 + r0 + row] = cfull + dsh;
  }
}

// ---------------- final v4: out = x + S'@x + const2 (verified) --------------
__global__ __launch_bounds__(256, 4) void final_v4_k(
    const float* __restrict__ x, float* __restrict__ out,
    const float* __restrict__ ws) {
  __shared__ __align__(16) char xs[32768];
  int b = blockIdx.y, n0 = blockIdx.x * 64;
  int t = threadIdx.x, lane = t & 63, w = t >> 6;
  int r31 = lane & 31, hi = lane >> 5;
  const half_t* Sb = (const half_t*)(ws + OFF_S16) + (size_t)b * 65536;
  const float* xb = x + (size_t)b * (C_ * (size_t)N_);
  {
    int n4 = (t & 15) * 4, cb = (t >> 4) * 4;
#pragma unroll
    for (int p = 0; p < 4; ++p) {
      int c = cb + p * 64;
      float a[4][4];
#pragma unroll
      for (int i = 0; i < 4; ++i) {
        float4 v = *(const float4*)(xb + (size_t)(c + i) * N_ + n0 + n4);
        a[i][0] = v.x; a[i][1] = v.y; a[i][2] = v.z; a[i][3] = v.w;
      }
#pragma unroll
      for (int j = 0; j < 4; ++j) {
        int n = n4 + j;
        union { half_t h[4]; uint2 u; } P;
        P.h[0] = (half_t)a[0][j]; P.h[1] = (half_t)a[1][j];
        P.h[2] = (half_t)a[2][j]; P.h[3] = (half_t)a[3][j];
        int g = ((cb >> 3) & 7) ^ ((n >> 3) & 7) ^ (n & 7);
        *(uint2*)(xs + p * 8192 + n * 128 + g * 16 + (cb & 7) * 2) = P.u;
      }
    }
  }
  __syncthreads();
  f32x16 acc[2][2] = {};
  int obase = w * 64;
  const half_t* Arow0 = Sb + (size_t)(obase + r31) * 256;
  const half_t* Arow1 = Sb + (size_t)(obase + 32 + r31) * 256;
  f16x8 An0[2], An1[2];
  An0[0] = *(const f16x8*)(Arow0 + hi * 8);
  An0[1] = *(const f16x8*)(Arow1 + hi * 8);
  An1[0] = *(const f16x8*)(Arow0 + 16 + hi * 8);
  An1[1] = *(const f16x8*)(Arow1 + 16 + hi * 8);
#pragma unroll
  for (int kk = 0; kk < 16; ++kk) {
    f16x8 Af[2];
    if (kk & 1) { Af[0] = An1[0]; Af[1] = An1[1]; }
    else        { Af[0] = An0[0]; Af[1] = An0[1]; }
    if (kk < 14) {
      int ck2 = (kk + 2) * 16 + hi * 8;
      if (kk & 1) { An1[0] = *(const f16x8*)(Arow0 + ck2); An1[1] = *(const f16x8*)(Arow1 + ck2); }
      else        { An0[0] = *(const f16x8*)(Arow0 + ck2); An0[1] = *(const f16x8*)(Arow1 + ck2); }
    }
    int ck = kk * 16 + hi * 8;
    int q = ck >> 6, ch = (ck >> 3) & 7;
    f16x8 Bf[2];
#pragma unroll
    for (int n = 0; n < 2; ++n) {
      int col = n * 32 + r31;
      int g = ch ^ ((col >> 3) & 7) ^ (col & 7);
      Bf[n] = *(const f16x8*)(xs + q * 8192 + col * 128 + g * 16);
    }
#pragma unroll
    for (int m = 0; m < 2; ++m)
#pragma unroll
      for (int n = 0; n < 2; ++n)
        acc[m][n] = __builtin_amdgcn_mfma_f32_32x32x16_f16(Af[m], Bf[n], acc[m][n], 0, 0, 0);
  }
  float* ob = out + (size_t)b * (C_ * (size_t)N_);
  const float* cstb = ws + OFF_CONST + b * 256;
#pragma unroll
  for (int m = 0; m < 2; ++m)
#pragma unroll
    for (int r = 0; r < 16; ++r) {
      int o = obase + m * 32 + (r & 3) + 8 * (r >> 2) + 4 * hi;
      float cv = cstb[o];
      size_t base = (size_t)o * N_ + n0;
      int q = o >> 6, ch = (o >> 3) & 7;
#pragma unroll
      for (int n = 0; n < 2; ++n) {
        int col = n * 32 + r31;
        int g = ch ^ ((col >> 3) & 7) ^ (col & 7);
        float xr = (float)*(const half_t*)(xs + q * 8192 + col * 128 + g * 16 + (o & 7) * 2);
        ob[base + col] = acc[m][n][r] + xr + cv;
      }
    }
}

extern "C" void kernel_launch(void* const* d_in, const int* in_sizes, int n_in,
                              void* d_out, int out_size, void* d_ws,
                              size_t ws_size, hipStream_t stream) {
  const float* x = (const float*)d_in[0];
  const float* gw = (const float*)d_in[1];
  const float* gb = (const float*)d_in[2];
  const float* qkvw = (const float*)d_in[3];
  const float* qkvb = (const float*)d_in[4];
  const float* pw = (const float*)d_in[5];
  const float* pb = (const float*)d_in[6];
  float* out = (float*)d_out;
  float* ws = (float*)d_ws;

  hipLaunchKernelGGL(gram_v5_k, dim3(1024), dim3(256), 0, stream, x, ws);
  hipLaunchKernelGGL(prep2_k, dim3(32), dim3(256), 0, stream, gw, gb, qkvw, ws);
  hipLaunchKernelGGL(gsum2_k, dim3(2048), dim3(256), 0, stream, ws);
  hipLaunchKernelGGL(wvt2_k, dim3(4, 4), dim3(256), 0, stream, qkvw, ws);
  hipLaunchKernelGGL(logits2_k, dim3(8, 32), dim3(256), 0, stream, qkvw, qkvb, ws);
  hipLaunchKernelGGL(fused_s_k, dim3(8, 32), dim3(256), 0, stream, pw, pb, ws);
  hipLaunchKernelGGL(final_v4_k, dim3(64, 32), dim3(256), 0, stream, x, out, ws);
}

// Round 10
// 210.555 us; speedup vs baseline: 1.0405x; 1.0405x over previous
//
#include <hip/hip_runtime.h>

// SelfAttention block:
//   gram_v6 : = verified gram_v4 (8-wave, 128B-row swizzle) with raw
//             s_barrier + lgkmcnt(0) instead of __syncthreads(), so the
//             chunk c+2 global prefetch survives the barrier (no vmcnt drain).
//   prep2   : group stats -> sc/sh, rall(q,k), u/v correction vectors
//   gsum2   : Graw[b] = sum of 8 slabs -> f16 h|l planes
//   wvt2    : Wv^T -> f16 (tiled transpose)
//   logits2 : T1=(Wq*sc)@Graw, L=T1@(Wk*sc)^T + rank-2 corr, softmax, A^T, cv
//   fused_s : T2=Pw@A, S'=(T2@Wv)*sc -> f16, const2
//   final_v4: out = x(f16 LDS) + S'@x + const2; swizzled b128 reads

#define B_ 32
#define C_ 256
#define N_ 4096
#define GSIZE (32 * N_)
#define EPSV 1e-5f
#define SCALE 0.0625f

// workspace layout (float units)
#define OFF_SC    0
#define OFF_SH    8192
#define OFF_RS    16384
#define OFF_RSP   24576                 // [b*8+ks][256]
#define OFF_SQP   90112                 // [b*8+ks][256]
#define OFF_RALL  155648                // [b][768] (q,k used)
#define OFF_UV    180224                // [b][4][256] = uq,vq,uk,vk
#define OFF_CV    212992
#define OFF_CONST 221184
#define OFF_WVT   229376                // f16 [256][256]
#define OFF_GH    262144                // f16 [b][256][256] high
#define OFF_GL    1310720               // f16 [b][256][256] low
#define OFF_AT    2359296               // fp32 [b][j][r]
#define OFF_S16   4456448               // f16 [b][o][c]  (S' = S*sc)
#define OFF_GP    5505024               // f16 slabs [b*8+ks][65536]

typedef _Float16 half_t;
typedef half_t f16x8 __attribute__((ext_vector_type(8)));
typedef float f32x16 __attribute__((ext_vector_type(16)));

// Barrier WITHOUT the vmcnt drain __syncthreads() would emit: LDS writes are
// made visible (lgkmcnt(0)) but global prefetch loads stay in flight.
#define GBAR()                                             \
  do {                                                     \
    asm volatile("s_waitcnt lgkmcnt(0)" ::: "memory");     \
    __builtin_amdgcn_sched_barrier(0);                     \
    __builtin_amdgcn_s_barrier();                          \
  } while (0)

// ---------------- Gram v6: v4 structure + non-draining barrier --------------
__global__ __launch_bounds__(512, 1) void gram_v6_k(const float* __restrict__ x,
                                                    float* __restrict__ ws) {
  __shared__ __align__(16) char hb[2][32768];  // [buf][256 rows][128B] swizzled
  int b = blockIdx.x >> 3, ks = blockIdx.x & 7;
  int t = threadIdx.x;
  const float* xb = x + (size_t)b * (C_ * (size_t)N_) + ks * 512;
  int lane = t & 63, w = t >> 6;
  int wm = w >> 2, wn = w & 3, r31 = lane & 31, hi = lane >> 5;
  int lrow = t >> 4, lc4 = t & 15;
  const float* lbase = xb + (size_t)lrow * N_ + lc4 * 4;
  f32x16 acc[4][2] = {};
  float4 stg[2][8];
  float rs[8] = {0.f, 0.f, 0.f, 0.f, 0.f, 0.f, 0.f, 0.f};
  float rq[8] = {0.f, 0.f, 0.f, 0.f, 0.f, 0.f, 0.f, 0.f};

#define LOADV(sb, c)                                                      \
  _Pragma("unroll") for (int p = 0; p < 8; ++p)                           \
      stg[sb][p] = *(const float4*)(lbase + (size_t)p * 32 * N_ + (c) * 64);

#define WRITEV(sb, buf)                                                   \
  {                                                                       \
    char* bp = hb[buf];                                                   \
    _Pragma("unroll") for (int p = 0; p < 8; ++p) {                       \
      float4 v = stg[sb][p];                                              \
      rs[p] += v.x + v.y + v.z + v.w;                                     \
      rq[p] += v.x * v.x + v.y * v.y + v.z * v.z + v.w * v.w;             \
      union { half_t h[4]; uint2 u; } H;                                  \
      H.h[0] = (half_t)v.x; H.h[1] = (half_t)v.y;                         \
      H.h[2] = (half_t)v.z; H.h[3] = (half_t)v.w;                         \
      int row = lrow + p * 32;                                            \
      int slot = (lc4 >> 1) ^ (row & 7);                                  \
      *(uint2*)(bp + row * 128 + slot * 16 + (lc4 & 1) * 8) = H.u;        \
    }                                                                     \
  }

  LOADV(0, 0);
  LOADV(1, 1);
  WRITEV(0, 0);
  GBAR();
  for (int c = 0; c < 8; ++c) {
    int buf = c & 1;
#pragma unroll
    for (int kk = 0; kk < 4; ++kk) {
      int kb = kk * 32 + hi * 16;
      f16x8 Af[4], Bf[2];
#pragma unroll
      for (int m = 0; m < 4; ++m) {
        int row = wm * 128 + m * 32 + r31;
        Af[m] = *(const f16x8*)(hb[buf] + row * 128 + (((kb >> 4) ^ (row & 7)) * 16));
      }
#pragma unroll
      for (int n = 0; n < 2; ++n) {
        int row = wn * 64 + n * 32 + r31;
        Bf[n] = *(const f16x8*)(hb[buf] + row * 128 + (((kb >> 4) ^ (row & 7)) * 16));
      }
#pragma unroll
      for (int m = 0; m < 4; ++m)
#pragma unroll
        for (int n = 0; n < 2; ++n)
          acc[m][n] = __builtin_amdgcn_mfma_f32_32x32x16_f16(Af[m], Bf[n], acc[m][n], 0, 0, 0);
    }
    if (c < 7) {
      int nb = (c + 1) & 1;          // staging/buffer holding chunk c+1
      WRITEV(nb, nb);
      if (c < 6) LOADV(buf, c + 2);  // chunk c+2 parity = c&1
      GBAR();
    }
  }
#pragma unroll
  for (int p = 0; p < 8; ++p) {
    float s = rs[p], q = rq[p];
    s += __shfl_xor(s, 1); s += __shfl_xor(s, 2);
    s += __shfl_xor(s, 4); s += __shfl_xor(s, 8);
    q += __shfl_xor(q, 1); q += __shfl_xor(q, 2);
    q += __shfl_xor(q, 4); q += __shfl_xor(q, 8);
    if ((t & 15) == 0) {
      int row = lrow + p * 32;
      ws[OFF_RSP + (size_t)blockIdx.x * 256 + row] = s;
      ws[OFF_SQP + (size_t)blockIdx.x * 256 + row] = q;
    }
  }
  half_t* Gp = (half_t*)(ws + OFF_GP) + (size_t)blockIdx.x * 65536;
#pragma unroll
  for (int m = 0; m < 4; ++m)
#pragma unroll
    for (int n = 0; n < 2; ++n)
#pragma unroll
      for (int r = 0; r < 16; ++r) {
        int gr = wm * 128 + m * 32 + (r & 3) + 8 * (r >> 2) + 4 * hi;
        int gc = wn * 64 + n * 32 + r31;
        Gp[gr * 256 + gc] = (half_t)acc[m][n][r];
      }
#undef LOADV
#undef WRITEV
}

// ---------------- gsum2: Graw = sum of slabs -> f16 h|l planes --------------
__global__ __launch_bounds__(256) void gsum2_k(float* __restrict__ ws) {
  int bx = blockIdx.x;  // 2048 = 32 b x 64 seg
  int b = bx >> 6, seg = bx & 63;
  int e0 = seg * 1024 + threadIdx.x * 4;
  const half_t* Gp = (const half_t*)(ws + OFF_GP) + (size_t)b * 8 * 65536 + e0;
  float s[4] = {0.f, 0.f, 0.f, 0.f};
#pragma unroll
  for (int ks = 0; ks < 8; ++ks) {
    union { uint2 u; half_t h[4]; } P;
    P.u = *(const uint2*)(Gp + (size_t)ks * 65536);
#pragma unroll
    for (int i = 0; i < 4; ++i) s[i] += (float)P.h[i];
  }
  union { half_t h[4]; uint2 u; } H, L;
#pragma unroll
  for (int i = 0; i < 4; ++i) {
    H.h[i] = (half_t)s[i];
    L.h[i] = (half_t)(s[i] - (float)H.h[i]);
  }
  *(uint2*)((half_t*)(ws + OFF_GH) + (size_t)b * 65536 + e0) = H.u;
  *(uint2*)((half_t*)(ws + OFF_GL) + (size_t)b * 65536 + e0) = L.u;
}

// ---------------- prep2: stats, sc/sh, rall(q,k), u/v vectors ---------------
__global__ __launch_bounds__(256) void prep2_k(const float* __restrict__ gw,
                                               const float* __restrict__ gb,
                                               const float* __restrict__ qkvw,
                                               float* __restrict__ ws) {
  int b = blockIdx.x, t = threadIdx.x;
  __shared__ float sL[256], qL[256], svecs[256], scrs[256], shsm[256];
  __shared__ float gmean[8], grstd[8];
  float s = 0.f, q = 0.f;
#pragma unroll
  for (int ks = 0; ks < 8; ++ks) {
    s += ws[OFF_RSP + (b * 8 + ks) * 256 + t];
    q += ws[OFF_SQP + (b * 8 + ks) * 256 + t];
  }
  ws[OFF_RS + b * 256 + t] = s;
  sL[t] = s; qL[t] = q;
  __syncthreads();
  if (t < 8) {
    float gs = 0.f, gq = 0.f;
    for (int i = 0; i < 32; ++i) { gs += sL[t * 32 + i]; gq += qL[t * 32 + i]; }
    float mean = gs * (1.f / GSIZE);
    float var = gq * (1.f / GSIZE) - mean * mean;
    gmean[t] = mean;
    grstd[t] = rsqrtf(var + EPSV);
  }
  __syncthreads();
  int g = t >> 5;
  float sc = grstd[g] * gw[t];
  float sh = gb[t] - gmean[g] * sc;
  ws[OFF_SC + b * 256 + t] = sc;
  ws[OFF_SH + b * 256 + t] = sh;
  svecs[t] = s * sc + 4096.f * sh;
  scrs[t] = s * sc;   // sc .* rs
  shsm[t] = sh;
  __syncthreads();
  {
    const float* r1 = qkvw + (size_t)t * 256;
    float rq = 0.f, uq = 0.f, vq = 0.f;
#pragma unroll 4
    for (int c = 0; c < 256; ++c) {
      float wv = r1[c];
      rq += wv * svecs[c]; uq += wv * scrs[c]; vq += wv * shsm[c];
    }
    ws[OFF_RALL + b * 768 + t] = rq;
    ws[OFF_UV + b * 1024 + t] = uq;
    ws[OFF_UV + b * 1024 + 256 + t] = vq;
  }
  {
    const float* r2 = qkvw + (size_t)(256 + t) * 256;
    float rk = 0.f, uk = 0.f, vk = 0.f;
#pragma unroll 4
    for (int c = 0; c < 256; ++c) {
      float wv = r2[c];
      rk += wv * svecs[c]; uk += wv * scrs[c]; vk += wv * shsm[c];
    }
    ws[OFF_RALL + b * 768 + 256 + t] = rk;
    ws[OFF_UV + b * 1024 + 512 + t] = uk;
    ws[OFF_UV + b * 1024 + 768 + t] = vk;
  }
}

// ---------------- wvt2: tiled transpose Wv -> f16 WVT[e][d] -----------------
__global__ __launch_bounds__(256) void wvt2_k(const float* __restrict__ qkvw,
                                              float* __restrict__ ws) {
  __shared__ float sm[64][68];
  int be = blockIdx.x * 64, bd = blockIdx.y * 64;
  int t = threadIdx.x;
#pragma unroll
  for (int i = 0; i < 4; ++i) {
    int f = t + i * 256;
    int row = f >> 4, c4 = f & 15;  // row = d-local
    float4 v = *(const float4*)(qkvw + (size_t)(512 + bd + row) * 256 + be + c4 * 4);
    sm[row][c4 * 4 + 0] = v.x; sm[row][c4 * 4 + 1] = v.y;
    sm[row][c4 * 4 + 2] = v.z; sm[row][c4 * 4 + 3] = v.w;
  }
  __syncthreads();
  half_t* WVT = (half_t*)(ws + OFF_WVT);
#pragma unroll
  for (int i = 0; i < 4; ++i) {
    int f = t + i * 256;
    int el = f >> 4, d4 = (f & 15) * 4;
    union { half_t h[4]; uint2 u; } P;
#pragma unroll
    for (int k = 0; k < 4; ++k) P.h[k] = (half_t)sm[d4 + k][el];
    *(uint2*)(WVT + (size_t)(be + el) * 256 + bd + d4) = P.u;
  }
}

// ---------------- logits2: T1=(Wq sc)@Graw, L=T1@(Wk sc)^T, softmax ---------
__global__ __launch_bounds__(256) void logits2_k(
    const float* __restrict__ qkvw, const float* __restrict__ qkvb,
    float* __restrict__ ws) {
  int b = blockIdx.y, r0 = blockIdx.x * 32;
  int t = threadIdx.x, lane = t & 63, w = t >> 6, r31 = lane & 31, hi = lane >> 5;
  __shared__ __align__(16) char GHL[32768];  // [256][128B]
  __shared__ __align__(16) char AHL[8192];
  __shared__ float T1s[32][257];
  __shared__ float scs[256];
  __shared__ float bk_s[256], rk_s[256], uk_s[256], vk_s[256];
  __shared__ float bq_s[32], rq_s[32], uq_s[32], vq_s[32];
  scs[t] = ws[OFF_SC + b * 256 + t];
  bk_s[t] = qkvb[256 + t];
  rk_s[t] = ws[OFF_RALL + b * 768 + 256 + t];
  uk_s[t] = ws[OFF_UV + b * 1024 + 512 + t];
  vk_s[t] = ws[OFF_UV + b * 1024 + 768 + t];
  if (t < 32) {
    bq_s[t] = qkvb[r0 + t];
    rq_s[t] = ws[OFF_RALL + b * 768 + r0 + t];
    uq_s[t] = ws[OFF_UV + b * 1024 + r0 + t];
    vq_s[t] = ws[OFF_UV + b * 1024 + 256 + r0 + t];
  }
  __syncthreads();
  const half_t* Gh = (const half_t*)(ws + OFF_GH) + (size_t)b * 65536;
  const half_t* Gl = (const half_t*)(ws + OFF_GL) + (size_t)b * 65536;
  f32x16 acc[2] = {};
  // ---- step A: T1 = (Wq*sc) @ Graw, K=256, 32-k chunks ----
  for (int k0 = 0; k0 < 256; k0 += 32) {
    {  // A: Wq rows r0..+31, column-scaled, h-only
      int row = t >> 3, c4 = t & 7;
      float4 v = *(const float4*)(qkvw + (size_t)(r0 + row) * 256 + k0 + c4 * 4);
      union { half_t h[4]; uint2 u; } H;
      H.h[0] = (half_t)(v.x * scs[k0 + c4 * 4 + 0]);
      H.h[1] = (half_t)(v.y * scs[k0 + c4 * 4 + 1]);
      H.h[2] = (half_t)(v.z * scs[k0 + c4 * 4 + 2]);
      H.h[3] = (half_t)(v.w * scs[k0 + c4 * 4 + 3]);
      int s8 = row & 7;
      *(uint2*)(AHL + row * 128 + (((c4 >> 1) ^ s8) * 16) + (c4 & 1) * 8) = H.u;
    }
    {  // B: Graw rows (symmetric) from h|l planes — straight copy
#pragma unroll
      for (int p = 0; p < 8; ++p) {
        int f = t + p * 256;
        int row = f >> 3, ko = f & 7;
        const half_t* src = (ko < 4) ? Gh : Gl;
        uint4 v = *(const uint4*)(src + (size_t)row * 256 + k0 + (ko & 3) * 8);
        *(uint4*)(GHL + row * 128 + ((ko ^ (row & 7)) * 16)) = v;
      }
    }
    __syncthreads();
#pragma unroll
    for (int kk = 0; kk < 2; ++kk) {
      int kb = kk * 32 + hi * 16;
      int arow = r31;
      f16x8 Aq = *(const f16x8*)(AHL + arow * 128 + (((kb >> 4) ^ (arow & 7)) * 16));
#pragma unroll
      for (int n = 0; n < 2; ++n) {
        int row = w * 64 + n * 32 + r31;
        int s8 = row & 7;
        f16x8 Bh = *(const f16x8*)(GHL + row * 128 + (((kb >> 4) ^ s8) * 16));
        f16x8 Bl = *(const f16x8*)(GHL + row * 128 + ((((kb >> 4) + 4) ^ s8) * 16));
        acc[n] = __builtin_amdgcn_mfma_f32_32x32x16_f16(Aq, Bh, acc[n], 0, 0, 0);
        acc[n] = __builtin_amdgcn_mfma_f32_32x32x16_f16(Aq, Bl, acc[n], 0, 0, 0);
      }
    }
    __syncthreads();
  }
#pragma unroll
  for (int n = 0; n < 2; ++n)
#pragma unroll
    for (int r = 0; r < 16; ++r)
      T1s[(r & 3) + 8 * (r >> 2) + 4 * hi][w * 64 + n * 32 + r31] = acc[n][r];
  __syncthreads();
  // ---- step B: L = T1 @ (Wk*sc)^T, K=256, 64-k chunks ----
  f32x16 acc2[2] = {};
  for (int k0 = 0; k0 < 256; k0 += 64) {
    {  // T1 rows 0..31 h|l, 16-slot swizzle
      int row = t >> 3;
#pragma unroll
      for (int u = 0; u < 2; ++u) {
        int c4 = (t & 7) + u * 8;
        float vv[4];
#pragma unroll
        for (int j = 0; j < 4; ++j) vv[j] = T1s[row][k0 + c4 * 4 + j];
        union { half_t h[4]; uint2 u2; } H, L;
#pragma unroll
        for (int j = 0; j < 4; ++j) {
          half_t h = (half_t)vv[j];
          H.h[j] = h; L.h[j] = (half_t)(vv[j] - (float)h);
        }
        int s16 = row & 15;
        *(uint2*)(AHL + row * 256 + (((c4 >> 1) ^ s16) * 16) + (c4 & 1) * 8) = H.u2;
        *(uint2*)(AHL + row * 256 + ((((c4 >> 1) + 8) ^ s16) * 16) + (c4 & 1) * 8) = L.u2;
      }
    }
    {  // Wk rows, column-scaled, h-only
#pragma unroll
      for (int p = 0; p < 16; ++p) {
        int f = t + p * 256;
        int row = f >> 4, c4 = f & 15;
        float4 v = *(const float4*)(qkvw + (size_t)(256 + row) * 256 + k0 + c4 * 4);
        union { half_t h[4]; uint2 u; } H;
        H.h[0] = (half_t)(v.x * scs[k0 + c4 * 4 + 0]);
        H.h[1] = (half_t)(v.y * scs[k0 + c4 * 4 + 1]);
        H.h[2] = (half_t)(v.z * scs[k0 + c4 * 4 + 2]);
        H.h[3] = (half_t)(v.w * scs[k0 + c4 * 4 + 3]);
        int slot = (c4 >> 1) ^ (row & 7);
        *(uint2*)(GHL + row * 128 + slot * 16 + (c4 & 1) * 8) = H.u;
      }
    }
    __syncthreads();
#pragma unroll
    for (int kk = 0; kk < 4; ++kk) {
      int kb = kk * 32 + hi * 16;
      int arow = r31;
      int s16 = arow & 15;
      f16x8 Ah = *(const f16x8*)(AHL + arow * 256 + (((kb >> 4) ^ s16) * 16));
      f16x8 Al = *(const f16x8*)(AHL + arow * 256 + ((((kb >> 4) + 8) ^ s16) * 16));
#pragma unroll
      for (int n = 0; n < 2; ++n) {
        int row = w * 64 + n * 32 + r31;
        f16x8 Bf = *(const f16x8*)(GHL + row * 128 + (((kb >> 4) ^ (row & 7)) * 16));
        acc2[n] = __builtin_amdgcn_mfma_f32_32x32x16_f16(Ah, Bf, acc2[n], 0, 0, 0);
        acc2[n] = __builtin_amdgcn_mfma_f32_32x32x16_f16(Al, Bf, acc2[n], 0, 0, 0);
      }
    }
    __syncthreads();
  }
  // rank-2 + bias corrections, store logits
#pragma unroll
  for (int n = 0; n < 2; ++n)
#pragma unroll
    for (int r = 0; r < 16; ++r) {
      int rr = (r & 3) + 8 * (r >> 2) + 4 * hi;
      int cc = w * 64 + n * 32 + r31;
      float v = acc2[n][r];
      float ukv = uk_s[cc] + 4096.f * vk_s[cc];
      v = (v + uq_s[rr] * vk_s[cc] + vq_s[rr] * ukv + bq_s[rr] * rk_s[cc] +
           bk_s[cc] * (rq_s[rr] + 4096.f * bq_s[rr])) * SCALE;
      T1s[rr][cc] = v;
    }
  __syncthreads();
  bk_s[t] = qkvb[512 + t];
  __syncthreads();
  {  // softmax: 8 threads per row
    int row = t >> 3, ls = t & 7;
    float m = -1e30f;
#pragma unroll
    for (int i = 0; i < 32; ++i) m = fmaxf(m, T1s[row][ls + i * 8]);
    m = fmaxf(m, __shfl_xor(m, 1));
    m = fmaxf(m, __shfl_xor(m, 2));
    m = fmaxf(m, __shfl_xor(m, 4));
    float s = 0.f, cvp = 0.f;
#pragma unroll
    for (int i = 0; i < 32; ++i) {
      int col = ls + i * 8;
      float e = __expf(T1s[row][col] - m);
      T1s[row][col] = e;
      s += e;
      cvp += e * bk_s[col];
    }
    s += __shfl_xor(s, 1); s += __shfl_xor(s, 2); s += __shfl_xor(s, 4);
    cvp += __shfl_xor(cvp, 1); cvp += __shfl_xor(cvp, 2); cvp += __shfl_xor(cvp, 4);
    float inv = 1.f / s;
#pragma unroll
    for (int i = 0; i < 32; ++i) T1s[row][ls + i * 8] *= inv;
    if (ls == 0) ws[OFF_CV + b * 256 + r0 + row] = cvp * inv;
  }
  __syncthreads();
  {  // transposed write: AT[b][j][r0..r0+31]
    float* ATb = ws + OFF_AT + (size_t)b * 65536;
#pragma unroll
    for (int u = 0; u < 8; ++u) {
      float4 v = {T1s[u * 4 + 0][t], T1s[u * 4 + 1][t], T1s[u * 4 + 2][t],
                  T1s[u * 4 + 3][t]};
      *(float4*)(ATb + (size_t)t * 256 + r0 + u * 4) = v;
    }
  }
}

// ---------------- fused S: T2=Pw@A, S'=(T2@Wv)*sc f16, const2 ---------------
__global__ __launch_bounds__(256) void fused_s_k(const float* __restrict__ pw,
                                                 const float* __restrict__ pb,
                                                 float* __restrict__ ws) {
  int b = blockIdx.y, r0 = blockIdx.x * 32;
  int t = threadIdx.x, lane = t & 63, w = t >> 6, r31 = lane & 31, hi = lane >> 5;
  __shared__ __align__(16) char GHL[32768];
  __shared__ __align__(16) char AHL[8192];
  __shared__ float T1s[32][257];
  __shared__ float cvs[256], scv[256], shv[256];
  cvs[t] = ws[OFF_CV + b * 256 + t];
  scv[t] = ws[OFF_SC + b * 256 + t];
  shv[t] = ws[OFF_SH + b * 256 + t];
  __syncthreads();
  const float* ATb = ws + OFF_AT + (size_t)b * 65536;
  f32x16 acc[2] = {};
  for (int k0 = 0; k0 < 256; k0 += 64) {
    {
#pragma unroll
      for (int p = 0; p < 2; ++p) {
        int f = t + p * 256;
        int row = f >> 4, c4 = f & 15;
        float4 v = *(const float4*)(pw + (size_t)(r0 + row) * 256 + k0 + c4 * 4);
        union { half_t h[4]; uint2 u; } H;
        H.h[0] = (half_t)v.x; H.h[1] = (half_t)v.y;
        H.h[2] = (half_t)v.z; H.h[3] = (half_t)v.w;
        int slot = (c4 >> 1) ^ (row & 7);
        *(uint2*)(AHL + row * 128 + slot * 16 + (c4 & 1) * 8) = H.u;
      }
    }
    {
#pragma unroll
      for (int p = 0; p < 16; ++p) {
        int f = t + p * 256;
        int row = f >> 4, c4 = f & 15;
        float4 v = *(const float4*)(ATb + (size_t)row * 256 + k0 + c4 * 4);
        union { half_t h[4]; uint2 u; } H;
        H.h[0] = (half_t)v.x; H.h[1] = (half_t)v.y;
        H.h[2] = (half_t)v.z; H.h[3] = (half_t)v.w;
        int slot = (c4 >> 1) ^ (row & 7);
        *(uint2*)(GHL + row * 128 + slot * 16 + (c4 & 1) * 8) = H.u;
      }
    }
    __syncthreads();
#pragma unroll
    for (int kk = 0; kk < 4; ++kk) {
      int kb = kk * 32 + hi * 16;
      int arow = r31;
      f16x8 Af = *(const f16x8*)(AHL + arow * 128 + (((kb >> 4) ^ (arow & 7)) * 16));
#pragma unroll
      for (int n = 0; n < 2; ++n) {
        int row = w * 64 + n * 32 + r31;
        f16x8 Bf = *(const f16x8*)(GHL + row * 128 + (((kb >> 4) ^ (row & 7)) * 16));
        acc[n] = __builtin_amdgcn_mfma_f32_32x32x16_f16(Af, Bf, acc[n], 0, 0, 0);
      }
    }
    __syncthreads();
  }
#pragma unroll
  for (int n = 0; n < 2; ++n)
#pragma unroll
    for (int r = 0; r < 16; ++r)
      T1s[(r & 3) + 8 * (r >> 2) + 4 * hi][w * 64 + n * 32 + r31] = acc[n][r];
  __syncthreads();
  float cfull = 0.f;
  {
    int row = t >> 3, ls = t & 7;
    float a = 0.f;
#pragma unroll
    for (int i = 0; i < 32; ++i) {
      int c = ls + i * 8;
      a += pw[(size_t)(r0 + row) * 256 + c] * cvs[c];
    }
    a += __shfl_xor(a, 1); a += __shfl_xor(a, 2); a += __shfl_xor(a, 4);
    cfull = a + pb[r0 + row];
  }
  const half_t* WVT = (const half_t*)(ws + OFF_WVT);
  f32x16 acc2[2] = {};
  for (int k0 = 0; k0 < 256; k0 += 64) {
    {
      int row = t >> 3;
#pragma unroll
      for (int u = 0; u < 2; ++u) {
        int c4 = (t & 7) + u * 8;
        float vv[4];
#pragma unroll
        for (int j = 0; j < 4; ++j) vv[j] = T1s[row][k0 + c4 * 4 + j];
        union { half_t h[4]; uint2 u2; } H, L;
#pragma unroll
        for (int j = 0; j < 4; ++j) {
          half_t h = (half_t)vv[j];
          H.h[j] = h; L.h[j] = (half_t)(vv[j] - (float)h);
        }
        int s16 = row & 15;
        *(uint2*)(AHL + row * 256 + (((c4 >> 1) ^ s16) * 16) + (c4 & 1) * 8) = H.u2;
        *(uint2*)(AHL + row * 256 + ((((c4 >> 1) + 8) ^ s16) * 16) + (c4 & 1) * 8) = L.u2;
      }
    }
    {
#pragma unroll
      for (int p = 0; p < 8; ++p) {
        int f = t + p * 256;
        int row = f >> 3, h8 = f & 7;
        uint2 v = *(const uint2*)(WVT + (size_t)row * 256 + k0 + h8 * 8);
        uint2 v2 = *(const uint2*)(WVT + (size_t)row * 256 + k0 + h8 * 8 + 4);
        int slot = h8 ^ (row & 7);
        *(uint2*)(GHL + row * 128 + slot * 16) = v;
        *(uint2*)(GHL + row * 128 + slot * 16 + 8) = v2;
      }
    }
    __syncthreads();
#pragma unroll
    for (int kk = 0; kk < 4; ++kk) {
      int kb = kk * 32 + hi * 16;
      int arow = r31;
      int s16 = arow & 15;
      f16x8 Ah = *(const f16x8*)(AHL + arow * 256 + (((kb >> 4) ^ s16) * 16));
      f16x8 Al = *(const f16x8*)(AHL + arow * 256 + ((((kb >> 4) + 8) ^ s16) * 16));
#pragma unroll
      for (int n = 0; n < 2; ++n) {
        int row = w * 64 + n * 32 + r31;
        f16x8 Bf = *(const f16x8*)(GHL + row * 128 + (((kb >> 4) ^ (row & 7)) * 16));
        acc2[n] = __builtin_amdgcn_mfma_f32_32x32x16_f16(Ah, Bf, acc2[n], 0, 0, 0);
        acc2[n] = __builtin_amdgcn_mfma_f32_32x32x16_f16(Al, Bf, acc2[n], 0, 0, 0);
      }
    }
    __syncthreads();
  }
#pragma unroll
  for (int n = 0; n < 2; ++n)
#pragma unroll
    for (int r = 0; r < 16; ++r)
      T1s[(r & 3) + 8 * (r >> 2) + 4 * hi][w * 64 + n * 32 + r31] = acc2[n][r];
  __syncthreads();
  {
    half_t* Sb = (half_t*)(ws + OFF_S16) + (size_t)b * 65536;
    int row = t >> 3, seg = t & 7;
    float dsh = 0.f;
#pragma unroll
    for (int u = 0; u < 4; ++u) {
      union { half_t h[8]; uint4 v; } P;
#pragma unroll
      for (int j = 0; j < 8; ++j) {
        int col = seg * 32 + u * 8 + j;
        float sv = T1s[row][col];
        dsh += sv * shv[col];
        P.h[j] = (half_t)(sv * scv[col]);
      }
      *(uint4*)(Sb + (size_t)(r0 + row) * 256 + seg * 32 + u * 8) = P.v;
    }
    dsh += __shfl_xor(dsh, 1); dsh += __shfl_xor(dsh, 2); dsh += __shfl_xor(dsh, 4);
    if (seg == 0) ws[OFF_CONST + b * 256 + r0 + row] = cfull + dsh;
  }
}

// ---------------- final v4: out = x + S'@x + const2 (verified) --------------
__global__ __launch_bounds__(256, 4) void final_v4_k(
    const float* __restrict__ x, float* __restrict__ out,
    const float* __restrict__ ws) {
  __shared__ __align__(16) char xs[32768];
  int b = blockIdx.y, n0 = blockIdx.x * 64;
  int t = threadIdx.x, lane = t & 63, w = t >> 6;
  int r31 = lane & 31, hi = lane >> 5;
  const half_t* Sb = (const half_t*)(ws + OFF_S16) + (size_t)b * 65536;
  const float* xb = x + (size_t)b * (C_ * (size_t)N_);
  {
    int n4 = (t & 15) * 4, cb = (t >> 4) * 4;
#pragma unroll
    for (int p = 0; p < 4; ++p) {
      int c = cb + p * 64;
      float a[4][4];
#pragma unroll
      for (int i = 0; i < 4; ++i) {
        float4 v = *(const float4*)(xb + (size_t)(c + i) * N_ + n0 + n4);
        a[i][0] = v.x; a[i][1] = v.y; a[i][2] = v.z; a[i][3] = v.w;
      }
#pragma unroll
      for (int j = 0; j < 4; ++j) {
        int n = n4 + j;
        union { half_t h[4]; uint2 u; } P;
        P.h[0] = (half_t)a[0][j]; P.h[1] = (half_t)a[1][j];
        P.h[2] = (half_t)a[2][j]; P.h[3] = (half_t)a[3][j];
        int g = ((cb >> 3) & 7) ^ ((n >> 3) & 7) ^ (n & 7);
        *(uint2*)(xs + p * 8192 + n * 128 + g * 16 + (cb & 7) * 2) = P.u;
      }
    }
  }
  __syncthreads();
  f32x16 acc[2][2] = {};
  int obase = w * 64;
  const half_t* Arow0 = Sb + (size_t)(obase + r31) * 256;
  const half_t* Arow1 = Sb + (size_t)(obase + 32 + r31) * 256;
  f16x8 An0[2], An1[2];
  An0[0] = *(const f16x8*)(Arow0 + hi * 8);
  An0[1] = *(const f16x8*)(Arow1 + hi * 8);
  An1[0] = *(const f16x8*)(Arow0 + 16 + hi * 8);
  An1[1] = *(const f16x8*)(Arow1 + 16 + hi * 8);
#pragma unroll
  for (int kk = 0; kk < 16; ++kk) {
    f16x8 Af[2];
    if (kk & 1) { Af[0] = An1[0]; Af[1] = An1[1]; }
    else        { Af[0] = An0[0]; Af[1] = An0[1]; }
    if (kk < 14) {
      int ck2 = (kk + 2) * 16 + hi * 8;
      if (kk & 1) { An1[0] = *(const f16x8*)(Arow0 + ck2); An1[1] = *(const f16x8*)(Arow1 + ck2); }
      else        { An0[0] = *(const f16x8*)(Arow0 + ck2); An0[1] = *(const f16x8*)(Arow1 + ck2); }
    }
    int ck = kk * 16 + hi * 8;
    int q = ck >> 6, ch = (ck >> 3) & 7;
    f16x8 Bf[2];
#pragma unroll
    for (int n = 0; n < 2; ++n) {
      int col = n * 32 + r31;
      int g = ch ^ ((col >> 3) & 7) ^ (col & 7);
      Bf[n] = *(const f16x8*)(xs + q * 8192 + col * 128 + g * 16);
    }
#pragma unroll
    for (int m = 0; m < 2; ++m)
#pragma unroll
      for (int n = 0; n < 2; ++n)
        acc[m][n] = __builtin_amdgcn_mfma_f32_32x32x16_f16(Af[m], Bf[n], acc[m][n], 0, 0, 0);
  }
  float* ob = out + (size_t)b * (C_ * (size_t)N_);
  const float* cstb = ws + OFF_CONST + b * 256;
#pragma unroll
  for (int m = 0; m < 2; ++m)
#pragma unroll
    for (int r = 0; r < 16; ++r) {
      int o = obase + m * 32 + (r & 3) + 8 * (r >> 2) + 4 * hi;
      float cv = cstb[o];
      size_t base = (size_t)o * N_ + n0;
      int q = o >> 6, ch = (o >> 3) & 7;
#pragma unroll
      for (int n = 0; n < 2; ++n) {
        int col = n * 32 + r31;
        int g = ch ^ ((col >> 3) & 7) ^ (col & 7);
        float xr = (float)*(const half_t*)(xs + q * 8192 + col * 128 + g * 16 + (o & 7) * 2);
        ob[base + col] = acc[m][n][r] + xr + cv;
      }
    }
}

extern "C" void kernel_launch(void* const* d_in, const int* in_sizes, int n_in,
                              void* d_out, int out_size, void* d_ws,
                              size_t ws_size, hipStream_t stream) {
  const float* x = (const float*)d_in[0];
  const float* gw = (const float*)d_in[1];
  const float* gb = (const float*)d_in[2];
  const float* qkvw = (const float*)d_in[3];
  const float* qkvb = (const float*)d_in[4];
  const float* pw = (const float*)d_in[5];
  const float* pb = (const float*)d_in[6];
  float* out = (float*)d_out;
  float* ws = (float*)d_ws;

  hipLaunchKernelGGL(gram_v6_k, dim3(256), dim3(512), 0, stream, x, ws);
  hipLaunchKernelGGL(prep2_k, dim3(32), dim3(256), 0, stream, gw, gb, qkvw, ws);
  hipLaunchKernelGGL(gsum2_k, dim3(2048), dim3(256), 0, stream, ws);
  hipLaunchKernelGGL(wvt2_k, dim3(4, 4), dim3(256), 0, stream, qkvw, ws);
  hipLaunchKernelGGL(logits2_k, dim3(8, 32), dim3(256), 0, stream, qkvw, qkvb, ws);
  hipLaunchKernelGGL(fused_s_k, dim3(8, 32), dim3(256), 0, stream, pw, pb, ws);
  hipLaunchKernelGGL(final_v4_k, dim3(64, 32), dim3(256), 0, stream, x, out, ws);
}